// Round 1
// baseline (752.532 us; speedup 1.0000x reference)
//
#include <hip/hip_runtime.h>
#include <stdint.h>

#define DEV __device__ __forceinline__

using bf16x8 = __attribute__((ext_vector_type(8))) __bf16;
using f32x4  = __attribute__((ext_vector_type(4))) float;

static constexpr int D    = 1024;
static constexpr int V    = 50257;
static constexpr int DFF  = 2048;
static constexpr int KD   = 3;     // depth
static constexpr int MR   = 512;   // padded rows per depth: r = b*256 + p
static constexpr int PLEN = 253;

DEV unsigned short f2b(float f) {
  unsigned int u = __float_as_uint(f);
  u += 0x7fffu + ((u >> 16) & 1u);   // RNE
  return (unsigned short)(u >> 16);
}

DEV void gload16(const void* g, void* l) {
  __builtin_amdgcn_global_load_lds(
      (const __attribute__((address_space(1))) unsigned int*)g,
      (__attribute__((address_space(3))) unsigned int*)l, 16, 0, 0);
}

// ---------- f32 -> bf16 bulk convert (n multiple of 4) ----------
__global__ void cvt_bf16(const float* __restrict__ src, unsigned short* __restrict__ dst, int n) {
  int i = blockIdx.x * blockDim.x + threadIdx.x;
  int stride = gridDim.x * blockDim.x;
  for (int j = i; j * 4 < n; j += stride) {
    float4 v = *(const float4*)(src + (size_t)j * 4);
    ushort4 o;
    o.x = f2b(v.x); o.y = f2b(v.y); o.z = f2b(v.z); o.w = f2b(v.w);
    *(ushort4*)(dst + (size_t)j * 4) = o;
  }
}

// ---------- h0 = x[:, :253] into padded 512-row layout ----------
__global__ __launch_bounds__(256) void init_h(const float* __restrict__ x, float* __restrict__ h) {
  int r = blockIdx.x, tid = threadIdx.x;
  int b = r >> 8, p = r & 255;
  float4 v = {0.f, 0.f, 0.f, 0.f};
  if (p < PLEN) v = *(const float4*)(x + ((size_t)(b * 256 + p)) * D + tid * 4);
  *(float4*)(h + (size_t)r * D + tid * 4) = v;
}

// ---------- merged = [rms(h), rms(e_k)] in bf16, one block per padded row ----------
__global__ __launch_bounds__(256) void rms_merge(
    const float* __restrict__ h, const float* __restrict__ x,
    const float* __restrict__ rw, unsigned short* __restrict__ merged, int koff)
{
  int r = blockIdx.x, tid = threadIdx.x;
  int b = r >> 8, p = r & 255;
  bool valid = p < PLEN;
  float4 hv = {0,0,0,0}, ev = {0,0,0,0};
  if (valid) {
    hv = *(const float4*)(h + (size_t)r * D + tid * 4);
    ev = *(const float4*)(x + ((size_t)(b * 256 + p + koff + 1)) * D + tid * 4);
  }
  float sh = hv.x*hv.x + hv.y*hv.y + hv.z*hv.z + hv.w*hv.w;
  float se = ev.x*ev.x + ev.y*ev.y + ev.z*ev.z + ev.w*ev.w;
  #pragma unroll
  for (int o = 32; o > 0; o >>= 1) { sh += __shfl_down(sh, o, 64); se += __shfl_down(se, o, 64); }
  __shared__ float ssh[4], sse[4];
  if ((tid & 63) == 0) { ssh[tid >> 6] = sh; sse[tid >> 6] = se; }
  __syncthreads();
  sh = ssh[0] + ssh[1] + ssh[2] + ssh[3];
  se = sse[0] + sse[1] + sse[2] + sse[3];
  float sc_h = rsqrtf(sh * (1.0f / D) + 1e-6f);
  float sc_e = rsqrtf(se * (1.0f / D) + 1e-6f);
  float4 wv = *(const float4*)(rw + tid * 4);
  ushort4 oh, oe;
  oh.x = f2b(hv.x * sc_h * wv.x); oh.y = f2b(hv.y * sc_h * wv.y);
  oh.z = f2b(hv.z * sc_h * wv.z); oh.w = f2b(hv.w * sc_h * wv.w);
  oe.x = f2b(ev.x * sc_e * wv.x); oe.y = f2b(ev.y * sc_e * wv.y);
  oe.z = f2b(ev.z * sc_e * wv.z); oe.w = f2b(ev.w * sc_e * wv.w);
  unsigned short* mrow = merged + (size_t)r * (2 * D);
  *(ushort4*)(mrow + tid * 4) = oh;
  *(ushort4*)(mrow + D + tid * 4) = oe;
}

// ---------- out = LayerNorm(ia + ib) * w + b ; writes f32 and bf16 ----------
__global__ __launch_bounds__(256) void add_ln(
    const float* __restrict__ ia, const float* __restrict__ ib,
    const float* __restrict__ w, const float* __restrict__ bb,
    float* __restrict__ of, unsigned short* __restrict__ ob)
{
  int r = blockIdx.x, tid = threadIdx.x;
  float4 va = *(const float4*)(ia + (size_t)r * D + tid * 4);
  float4 vb = *(const float4*)(ib + (size_t)r * D + tid * 4);
  float4 v = {va.x+vb.x, va.y+vb.y, va.z+vb.z, va.w+vb.w};
  float s  = v.x + v.y + v.z + v.w;
  float s2 = v.x*v.x + v.y*v.y + v.z*v.z + v.w*v.w;
  #pragma unroll
  for (int o = 32; o > 0; o >>= 1) { s += __shfl_down(s, o, 64); s2 += __shfl_down(s2, o, 64); }
  __shared__ float rs[4], rq[4];
  if ((tid & 63) == 0) { rs[tid >> 6] = s; rq[tid >> 6] = s2; }
  __syncthreads();
  s  = rs[0] + rs[1] + rs[2] + rs[3];
  s2 = rq[0] + rq[1] + rq[2] + rq[3];
  float m   = s * (1.0f / D);
  float var = s2 * (1.0f / D) - m * m;
  float sc  = rsqrtf(var + 1e-5f);
  float4 wv = *(const float4*)(w + tid * 4);
  float4 bv = *(const float4*)(bb + tid * 4);
  float4 o;
  o.x = (v.x - m) * sc * wv.x + bv.x;
  o.y = (v.y - m) * sc * wv.y + bv.y;
  o.z = (v.z - m) * sc * wv.z + bv.z;
  o.w = (v.w - m) * sc * wv.w + bv.w;
  *(float4*)(of + (size_t)r * D + tid * 4) = o;
  ushort4 ub; ub.x = f2b(o.x); ub.y = f2b(o.y); ub.z = f2b(o.z); ub.w = f2b(o.w);
  *(ushort4*)(ob + (size_t)r * D + tid * 4) = ub;
}

// ---------- generic C = A @ Bt^T (+bias) GEMM, bf16 in, f32 acc ----------
// A: M x K row-major bf16, Bt: N x K row-major bf16. 4 waves (2x2), tile 32WM x 32WN.
template<int WM, int WN, int BK, bool BIAS, bool RELU, bool OF32, bool OB16>
__global__ __launch_bounds__(256) void gemm_bt(
    const unsigned short* __restrict__ A, const unsigned short* __restrict__ Bt,
    const float* __restrict__ bias, float* __restrict__ Cf,
    unsigned short* __restrict__ Cb, int M, int N, int K)
{
  constexpr int BM = 32 * WM, BN = 32 * WN;
  constexpr int CPR = BK / 8;              // 16B chunks per LDS row
  constexpr int AI = BM * BK / 8 / 256;
  constexpr int BI = BN * BK / 8 / 256;
  static_assert(AI * 256 == BM * BK / 8, "A tile must be multiple of 4KB");
  static_assert(BI * 256 == BN * BK / 8, "B tile must be multiple of 4KB");
  __shared__ __align__(16) unsigned short As[BM * BK];
  __shared__ __align__(16) unsigned short Bs[BN * BK];
  const int tid = threadIdx.x;
  const int lane = tid & 63, wave = tid >> 6;
  const int wm = wave >> 1, wn = wave & 1;
  const int l16 = lane & 15, lk = lane >> 4;
  const int tm = blockIdx.y * BM, tn = blockIdx.x * BN;
  (void)M;

  f32x4 acc[WM][WN] = {};

  for (int k0 = 0; k0 < K; k0 += BK) {
    #pragma unroll
    for (int i = 0; i < AI; ++i) {
      int c = i * 256 + tid;
      gload16(A + (size_t)(tm + c / CPR) * K + k0 + (c % CPR) * 8, &As[c * 8]);
    }
    #pragma unroll
    for (int i = 0; i < BI; ++i) {
      int c = i * 256 + tid;
      gload16(Bt + (size_t)(tn + c / CPR) * K + k0 + (c % CPR) * 8, &Bs[c * 8]);
    }
    __syncthreads();   // drains vmcnt -> LDS tiles ready
    #pragma unroll
    for (int kk = 0; kk < BK / 32; ++kk) {
      bf16x8 af[WM], bg[WN];
      #pragma unroll
      for (int mi = 0; mi < WM; ++mi)
        af[mi] = *(const bf16x8*)&As[(wm * 16 * WM + mi * 16 + l16) * BK + kk * 32 + lk * 8];
      #pragma unroll
      for (int ni = 0; ni < WN; ++ni)
        bg[ni] = *(const bf16x8*)&Bs[(wn * 16 * WN + ni * 16 + l16) * BK + kk * 32 + lk * 8];
      #pragma unroll
      for (int mi = 0; mi < WM; ++mi)
        #pragma unroll
        for (int ni = 0; ni < WN; ++ni)
          acc[mi][ni] = __builtin_amdgcn_mfma_f32_16x16x32_bf16(af[mi], bg[ni], acc[mi][ni], 0, 0, 0);
    }
    __syncthreads();   // everyone done reading before next stage
  }

  const int rbase = tm + wm * 16 * WM, cbase = tn + wn * 16 * WN;
  #pragma unroll
  for (int ni = 0; ni < WN; ++ni) {
    int col = cbase + ni * 16 + l16;
    float bvv = BIAS ? bias[col] : 0.0f;
    #pragma unroll
    for (int mi = 0; mi < WM; ++mi) {
      #pragma unroll
      for (int rr = 0; rr < 4; ++rr) {
        int row = rbase + mi * 16 + lk * 4 + rr;   // C/D: col=lane&15, row=(lane>>4)*4+reg
        float v = acc[mi][ni][rr] + bvv;
        if (RELU) v = fmaxf(v, 0.0f);
        size_t idx = (size_t)row * N + col;
        if (OF32) Cf[idx] = v;
        if (OB16) Cb[idx] = f2b(v);
      }
    }
  }
}

// ---------- logits: (3*512 padded rows) x V, remapped store to (b,p,k,v) ----------
__global__ __launch_bounds__(256) void gemm_logits(
    const unsigned short* __restrict__ A, const unsigned short* __restrict__ E,
    float* __restrict__ Out)
{
  constexpr int BM = 128, BN = 128, BK = 32, K = D;
  constexpr int CPR = BK / 8;   // 4
  __shared__ __align__(16) unsigned short As[BM * BK];
  __shared__ __align__(16) unsigned short Bs[BN * BK];
  const int tid = threadIdx.x;
  const int lane = tid & 63, wave = tid >> 6;
  const int wm = wave >> 1, wn = wave & 1;
  const int l16 = lane & 15, lk = lane >> 4;
  const int tm = blockIdx.x * BM;   // 12 M-tiles fast -> share embed panel
  const int tn = blockIdx.y * BN;   // 393 N-tiles

  f32x4 acc[4][4] = {};

  for (int k0 = 0; k0 < K; k0 += BK) {
    #pragma unroll
    for (int i = 0; i < 2; ++i) {
      int c = i * 256 + tid;
      gload16(A + (size_t)(tm + c / CPR) * K + k0 + (c % CPR) * 8, &As[c * 8]);
    }
    #pragma unroll
    for (int i = 0; i < 2; ++i) {
      int c = i * 256 + tid;
      int rg = tn + c / CPR; if (rg > V - 1) rg = V - 1;   // clamp OOB vocab rows
      gload16(E + (size_t)rg * K + k0 + (c % CPR) * 8, &Bs[c * 8]);
    }
    __syncthreads();
    bf16x8 af[4], bg[4];
    #pragma unroll
    for (int mi = 0; mi < 4; ++mi)
      af[mi] = *(const bf16x8*)&As[(wm * 64 + mi * 16 + l16) * BK + lk * 8];
    #pragma unroll
    for (int ni = 0; ni < 4; ++ni)
      bg[ni] = *(const bf16x8*)&Bs[(wn * 64 + ni * 16 + l16) * BK + lk * 8];
    #pragma unroll
    for (int mi = 0; mi < 4; ++mi)
      #pragma unroll
      for (int ni = 0; ni < 4; ++ni)
        acc[mi][ni] = __builtin_amdgcn_mfma_f32_16x16x32_bf16(af[mi], bg[ni], acc[mi][ni], 0, 0, 0);
    __syncthreads();
  }

  const int rbase = tm + wm * 64, cbase = tn + wn * 64;
  #pragma unroll
  for (int mi = 0; mi < 4; ++mi) {
    #pragma unroll
    for (int rr = 0; rr < 4; ++rr) {
      int row = rbase + mi * 16 + lk * 4 + rr;      // 0..1535 padded
      int kk = row >> 9, bp = row & 511, b = bp >> 8, p = bp & 255;
      if (p >= PLEN) continue;
      size_t obase = ((size_t)((b * PLEN + p) * KD + kk)) * V;
      #pragma unroll
      for (int ni = 0; ni < 4; ++ni) {
        int col = cbase + ni * 16 + l16;
        if (col < V) Out[obase + col] = acc[mi][ni][rr];
      }
    }
  }
}

extern "C" void kernel_launch(void* const* d_in, const int* in_sizes, int n_in,
                              void* d_out, int out_size, void* d_ws, size_t ws_size,
                              hipStream_t stream)
{
  (void)in_sizes; (void)n_in; (void)out_size; (void)ws_size;
  const float* x      = (const float*)d_in[0];
  const float* embedw = (const float*)d_in[1];
  const float* rmsw   = (const float*)d_in[2];
  const float* projw  = (const float*)d_in[3];
  const float* projb  = (const float*)d_in[4];
  const float* ainw   = (const float*)d_in[5];
  const float* ainb   = (const float*)d_in[6];
  const float* aoutw  = (const float*)d_in[7];
  const float* aoutb  = (const float*)d_in[8];
  const float* ff1w   = (const float*)d_in[9];
  const float* ff1b   = (const float*)d_in[10];
  const float* ff2w   = (const float*)d_in[11];
  const float* ff2b   = (const float*)d_in[12];
  const float* ln1w   = (const float*)d_in[13];
  const float* ln1b   = (const float*)d_in[14];
  const float* ln2w   = (const float*)d_in[15];
  const float* ln2b   = (const float*)d_in[16];
  float* out = (float*)d_out;

  char* ws = (char*)d_ws;
  size_t off = 0;
  auto alloc = [&](size_t bytes) -> void* {
    void* ptr = ws + off;
    off = (off + bytes + 255) & ~(size_t)255;
    return ptr;
  };
  unsigned short* embed_b = (unsigned short*)alloc((size_t)V * D * 2);
  unsigned short* projw_b = (unsigned short*)alloc((size_t)KD * D * 2 * D * 2);
  unsigned short* ainw_b  = (unsigned short*)alloc((size_t)KD * 3 * D * D * 2);
  unsigned short* aoutw_b = (unsigned short*)alloc((size_t)KD * D * D * 2);
  unsigned short* ff1w_b  = (unsigned short*)alloc((size_t)KD * DFF * D * 2);
  unsigned short* ff2w_b  = (unsigned short*)alloc((size_t)KD * D * DFF * 2);
  float*          h_f     = (float*)alloc((size_t)MR * D * 4);
  unsigned short* h_all   = (unsigned short*)alloc((size_t)KD * MR * D * 2);
  unsigned short* merged  = (unsigned short*)alloc((size_t)MR * 2 * D * 2);
  float*          p_f     = (float*)alloc((size_t)MR * D * 4);
  unsigned short* p_b     = (unsigned short*)alloc((size_t)MR * D * 2);
  unsigned short* v_b     = (unsigned short*)alloc((size_t)MR * D * 2);
  float*          sa_f    = (float*)alloc((size_t)MR * D * 4);
  float*          s1_f    = (float*)alloc((size_t)MR * D * 4);
  unsigned short* s1_b    = (unsigned short*)alloc((size_t)MR * D * 2);
  unsigned short* ff_b    = (unsigned short*)alloc((size_t)MR * DFF * 2);
  float*          ff2_f   = (float*)alloc((size_t)MR * D * 4);

  auto cvt = [&](const float* s, unsigned short* dgt, long n) {
    long n4 = n / 4;
    int blocks = (int)((n4 + 255) / 256);
    if (blocks > 4096) blocks = 4096;
    cvt_bf16<<<dim3(blocks), dim3(256), 0, stream>>>(s, dgt, (int)n);
  };
  cvt(embedw, embed_b, (long)V * D);
  cvt(projw,  projw_b, (long)KD * D * 2 * D);
  cvt(ainw,   ainw_b,  (long)KD * 3 * D * D);
  cvt(aoutw,  aoutw_b, (long)KD * D * D);
  cvt(ff1w,   ff1w_b,  (long)KD * DFF * D);
  cvt(ff2w,   ff2w_b,  (long)KD * D * DFF);

  init_h<<<dim3(MR), dim3(256), 0, stream>>>(x, h_f);

  for (int k = 0; k < KD; ++k) {
    rms_merge<<<dim3(MR), dim3(256), 0, stream>>>(h_f, x, rmsw, merged, k);
    // p = merged @ proj_w[k]^T + proj_b[k]   (M=512, N=1024, K=2048)
    gemm_bt<2,2,64,true,false,true,true><<<dim3(D/64, MR/64), dim3(256), 0, stream>>>(
        merged, projw_b + (size_t)k * D * 2 * D, projb + (size_t)k * D, p_f, p_b, MR, D, 2 * D);
    // v = p @ wv^T + bv  (wv = attn_in_w[k][2D:], 1024x1024)
    gemm_bt<2,2,64,true,false,false,true><<<dim3(D/64, MR/64), dim3(256), 0, stream>>>(
        p_b, ainw_b + (size_t)k * 3 * D * D + (size_t)2 * D * D, ainb + (size_t)k * 3 * D + 2 * D,
        (float*)nullptr, v_b, MR, D, D);
    // sa = v @ attn_out_w[k]^T + b
    gemm_bt<2,2,64,true,false,true,false><<<dim3(D/64, MR/64), dim3(256), 0, stream>>>(
        v_b, aoutw_b + (size_t)k * D * D, aoutb + (size_t)k * D, sa_f, (unsigned short*)nullptr, MR, D, D);
    // s1 = LN(p + sa)
    add_ln<<<dim3(MR), dim3(256), 0, stream>>>(p_f, sa_f, ln1w + (size_t)k * D, ln1b + (size_t)k * D, s1_f, s1_b);
    // ff = relu(s1 @ ff1_w[k]^T + b)   (N=2048)
    gemm_bt<2,2,64,true,true,false,true><<<dim3(DFF/64, MR/64), dim3(256), 0, stream>>>(
        s1_b, ff1w_b + (size_t)k * DFF * D, ff1b + (size_t)k * DFF, (float*)nullptr, ff_b, MR, DFF, D);
    // ff2 = ff @ ff2_w[k]^T + b        (K=2048)
    gemm_bt<2,2,64,true,false,true,false><<<dim3(D/64, MR/64), dim3(256), 0, stream>>>(
        ff_b, ff2w_b + (size_t)k * D * DFF, ff2b + (size_t)k * D, ff2_f, (unsigned short*)nullptr, MR, D, DFF);
    // h = LN(s1 + ff2) -> h_f (f32, next iter) + h_all[k] (bf16, logits)
    add_ln<<<dim3(MR), dim3(256), 0, stream>>>(s1_f, ff2_f, ln2w + (size_t)k * D, ln2b + (size_t)k * D,
                                               h_f, h_all + (size_t)k * MR * D);
  }

  // logits for all 3 depths in one batched GEMM: (1536 x 1024) @ (50257 x 1024)^T
  gemm_logits<<<dim3(KD * MR / 128, (V + 127) / 128), dim3(256), 0, stream>>>(h_all, embed_b, out);
}

// Round 2
// 655.566 us; speedup vs baseline: 1.1479x; 1.1479x over previous
//
#include <hip/hip_runtime.h>
#include <stdint.h>

#define DEV __device__ __forceinline__

using bf16x8 = __attribute__((ext_vector_type(8))) __bf16;
using f32x4  = __attribute__((ext_vector_type(4))) float;

static constexpr int D    = 1024;
static constexpr int V    = 50257;
static constexpr int DFF  = 2048;
static constexpr int KD   = 3;     // depth
static constexpr int MR   = 512;   // padded rows per depth: r = b*256 + p
static constexpr int PLEN = 253;

DEV unsigned short f2b(float f) {
  unsigned int u = __float_as_uint(f);
  u += 0x7fffu + ((u >> 16) & 1u);   // RNE
  return (unsigned short)(u >> 16);
}

DEV void gload16(const void* g, void* l) {
  __builtin_amdgcn_global_load_lds(
      (const __attribute__((address_space(1))) unsigned int*)g,
      (__attribute__((address_space(3))) unsigned int*)l, 16, 0, 0);
}

// ---------- f32 -> bf16 bulk convert (n multiple of 4) ----------
__global__ void cvt_bf16(const float* __restrict__ src, unsigned short* __restrict__ dst, int n) {
  int i = blockIdx.x * blockDim.x + threadIdx.x;
  int stride = gridDim.x * blockDim.x;
  for (int j = i; j * 4 < n; j += stride) {
    float4 v = *(const float4*)(src + (size_t)j * 4);
    ushort4 o;
    o.x = f2b(v.x); o.y = f2b(v.y); o.z = f2b(v.z); o.w = f2b(v.w);
    *(ushort4*)(dst + (size_t)j * 4) = o;
  }
}

// ---------- h0 = x[:, :253] into padded 512-row layout ----------
__global__ __launch_bounds__(256) void init_h(const float* __restrict__ x, float* __restrict__ h) {
  int r = blockIdx.x, tid = threadIdx.x;
  int b = r >> 8, p = r & 255;
  float4 v = {0.f, 0.f, 0.f, 0.f};
  if (p < PLEN) v = *(const float4*)(x + ((size_t)(b * 256 + p)) * D + tid * 4);
  *(float4*)(h + (size_t)r * D + tid * 4) = v;
}

// ---------- merged = [rms(h), rms(e_k)] in bf16, one block per padded row ----------
__global__ __launch_bounds__(256) void rms_merge(
    const float* __restrict__ h, const float* __restrict__ x,
    const float* __restrict__ rw, unsigned short* __restrict__ merged, int koff)
{
  int r = blockIdx.x, tid = threadIdx.x;
  int b = r >> 8, p = r & 255;
  bool valid = p < PLEN;
  float4 hv = {0,0,0,0}, ev = {0,0,0,0};
  if (valid) {
    hv = *(const float4*)(h + (size_t)r * D + tid * 4);
    ev = *(const float4*)(x + ((size_t)(b * 256 + p + koff + 1)) * D + tid * 4);
  }
  float sh = hv.x*hv.x + hv.y*hv.y + hv.z*hv.z + hv.w*hv.w;
  float se = ev.x*ev.x + ev.y*ev.y + ev.z*ev.z + ev.w*ev.w;
  #pragma unroll
  for (int o = 32; o > 0; o >>= 1) { sh += __shfl_down(sh, o, 64); se += __shfl_down(se, o, 64); }
  __shared__ float ssh[4], sse[4];
  if ((tid & 63) == 0) { ssh[tid >> 6] = sh; sse[tid >> 6] = se; }
  __syncthreads();
  sh = ssh[0] + ssh[1] + ssh[2] + ssh[3];
  se = sse[0] + sse[1] + sse[2] + sse[3];
  float sc_h = rsqrtf(sh * (1.0f / D) + 1e-6f);
  float sc_e = rsqrtf(se * (1.0f / D) + 1e-6f);
  float4 wv = *(const float4*)(rw + tid * 4);
  ushort4 oh, oe;
  oh.x = f2b(hv.x * sc_h * wv.x); oh.y = f2b(hv.y * sc_h * wv.y);
  oh.z = f2b(hv.z * sc_h * wv.z); oh.w = f2b(hv.w * sc_h * wv.w);
  oe.x = f2b(ev.x * sc_e * wv.x); oe.y = f2b(ev.y * sc_e * wv.y);
  oe.z = f2b(ev.z * sc_e * wv.z); oe.w = f2b(ev.w * sc_e * wv.w);
  unsigned short* mrow = merged + (size_t)r * (2 * D);
  *(ushort4*)(mrow + tid * 4) = oh;
  *(ushort4*)(mrow + D + tid * 4) = oe;
}

// ---------- out = LayerNorm(ia + ib) * w + b ; writes f32 and bf16 ----------
__global__ __launch_bounds__(256) void add_ln(
    const float* __restrict__ ia, const float* __restrict__ ib,
    const float* __restrict__ w, const float* __restrict__ bb,
    float* __restrict__ of, unsigned short* __restrict__ ob)
{
  int r = blockIdx.x, tid = threadIdx.x;
  float4 va = *(const float4*)(ia + (size_t)r * D + tid * 4);
  float4 vb = *(const float4*)(ib + (size_t)r * D + tid * 4);
  float4 v = {va.x+vb.x, va.y+vb.y, va.z+vb.z, va.w+vb.w};
  float s  = v.x + v.y + v.z + v.w;
  float s2 = v.x*v.x + v.y*v.y + v.z*v.z + v.w*v.w;
  #pragma unroll
  for (int o = 32; o > 0; o >>= 1) { s += __shfl_down(s, o, 64); s2 += __shfl_down(s2, o, 64); }
  __shared__ float rs[4], rq[4];
  if ((tid & 63) == 0) { rs[tid >> 6] = s; rq[tid >> 6] = s2; }
  __syncthreads();
  s  = rs[0] + rs[1] + rs[2] + rs[3];
  s2 = rq[0] + rq[1] + rq[2] + rq[3];
  float m   = s * (1.0f / D);
  float var = s2 * (1.0f / D) - m * m;
  float sc  = rsqrtf(var + 1e-5f);
  float4 wv = *(const float4*)(w + tid * 4);
  float4 bv = *(const float4*)(bb + tid * 4);
  float4 o;
  o.x = (v.x - m) * sc * wv.x + bv.x;
  o.y = (v.y - m) * sc * wv.y + bv.y;
  o.z = (v.z - m) * sc * wv.z + bv.z;
  o.w = (v.w - m) * sc * wv.w + bv.w;
  *(float4*)(of + (size_t)r * D + tid * 4) = o;
  ushort4 ub; ub.x = f2b(o.x); ub.y = f2b(o.y); ub.z = f2b(o.z); ub.w = f2b(o.w);
  *(ushort4*)(ob + (size_t)r * D + tid * 4) = ub;
}

// ---------- generic C = A @ Bt^T (+bias) GEMM, bf16 in, f32 acc ----------
template<int WM, int WN, int BK, bool BIAS, bool RELU, bool OF32, bool OB16>
__global__ __launch_bounds__(256) void gemm_bt(
    const unsigned short* __restrict__ A, const unsigned short* __restrict__ Bt,
    const float* __restrict__ bias, float* __restrict__ Cf,
    unsigned short* __restrict__ Cb, int M, int N, int K)
{
  constexpr int BM = 32 * WM, BN = 32 * WN;
  constexpr int CPR = BK / 8;              // 16B chunks per LDS row
  constexpr int AI = BM * BK / 8 / 256;
  constexpr int BI = BN * BK / 8 / 256;
  static_assert(AI * 256 == BM * BK / 8, "A tile must be multiple of 4KB");
  static_assert(BI * 256 == BN * BK / 8, "B tile must be multiple of 4KB");
  __shared__ __align__(16) unsigned short As[BM * BK];
  __shared__ __align__(16) unsigned short Bs[BN * BK];
  const int tid = threadIdx.x;
  const int lane = tid & 63, wave = tid >> 6;
  const int wm = wave >> 1, wn = wave & 1;
  const int l16 = lane & 15, lk = lane >> 4;
  const int tm = blockIdx.y * BM, tn = blockIdx.x * BN;
  (void)M;

  f32x4 acc[WM][WN] = {};

  for (int k0 = 0; k0 < K; k0 += BK) {
    #pragma unroll
    for (int i = 0; i < AI; ++i) {
      int c = i * 256 + tid;
      gload16(A + (size_t)(tm + c / CPR) * K + k0 + (c % CPR) * 8, &As[c * 8]);
    }
    #pragma unroll
    for (int i = 0; i < BI; ++i) {
      int c = i * 256 + tid;
      gload16(Bt + (size_t)(tn + c / CPR) * K + k0 + (c % CPR) * 8, &Bs[c * 8]);
    }
    __syncthreads();
    #pragma unroll
    for (int kk = 0; kk < BK / 32; ++kk) {
      bf16x8 af[WM], bg[WN];
      #pragma unroll
      for (int mi = 0; mi < WM; ++mi)
        af[mi] = *(const bf16x8*)&As[(wm * 16 * WM + mi * 16 + l16) * BK + kk * 32 + lk * 8];
      #pragma unroll
      for (int ni = 0; ni < WN; ++ni)
        bg[ni] = *(const bf16x8*)&Bs[(wn * 16 * WN + ni * 16 + l16) * BK + kk * 32 + lk * 8];
      #pragma unroll
      for (int mi = 0; mi < WM; ++mi)
        #pragma unroll
        for (int ni = 0; ni < WN; ++ni)
          acc[mi][ni] = __builtin_amdgcn_mfma_f32_16x16x32_bf16(af[mi], bg[ni], acc[mi][ni], 0, 0, 0);
    }
    __syncthreads();
  }

  const int rbase = tm + wm * 16 * WM, cbase = tn + wn * 16 * WN;
  #pragma unroll
  for (int ni = 0; ni < WN; ++ni) {
    int col = cbase + ni * 16 + l16;
    float bvv = BIAS ? bias[col] : 0.0f;
    #pragma unroll
    for (int mi = 0; mi < WM; ++mi) {
      #pragma unroll
      for (int rr = 0; rr < 4; ++rr) {
        int row = rbase + mi * 16 + lk * 4 + rr;
        float v = acc[mi][ni][rr] + bvv;
        if (RELU) v = fmaxf(v, 0.0f);
        size_t idx = (size_t)row * N + col;
        if (OF32) Cf[idx] = v;
        if (OB16) Cb[idx] = f2b(v);
      }
    }
  }
}

// ---------- logits: 256x256 tile, BK=64, 8-wave, 8-phase counted-vmcnt pipeline ----------
// LDS halves: [parity][khalf] of 256 rows x 32 k bf16 (16 KB each) per operand = 128 KiB.
// Issue order per tile j: A0(j),B0(j),A1(j),B1(j); 1 half/phase; 6-half prologue lead.
// vmcnt(8) (=4 halves in flight) at P1-end & P3-end before the raw barrier gives exact
// cross-wave coverage of the halves read by the next phases. Never drains in-loop.
__global__ __launch_bounds__(512, 2) void gemm_logits8(
    const unsigned short* __restrict__ A, const unsigned short* __restrict__ E,
    float* __restrict__ Out)
{
  constexpr int NT  = 16;            // K=1024 / BK=64
  constexpr int NWG = 6 * 197;       // M-tiles x N-tiles
  __shared__ __align__(16) unsigned short Asl[2][2][8192];
  __shared__ __align__(16) unsigned short Bsl[2][2][8192];

  const int tid  = threadIdx.x;
  const int lane = tid & 63, wave = tid >> 6;
  const int wm = wave >> 2, wn = wave & 3;
  const int l16 = lane & 15, lk = lane >> 4;
  const int swl = (l16 ^ (l16 >> 2)) & 3;          // row-derived swizzle, lane-uniform
  const int rchunk = ((lk ^ swl) & 3) * 8;         // ushort offset of 16B chunk in a 64B row

  // bijective XCD swizzle (m204): nwg = 1182 = 8*147 + 6
  int orig = blockIdx.x;
  int xcd = orig & 7, local = orig >> 3;
  constexpr int q = NWG / 8, r8 = NWG % 8;
  int wgid = (xcd < r8 ? xcd * (q + 1) : r8 * (q + 1) + (xcd - r8) * q) + local;
  const int tm = (wgid % 6) * 256;
  const int tn = (wgid / 6) * 256;

  f32x4 acc[8][4] = {};
  bf16x8 af[8];

  auto stageA = [&](int j, int kh, int pi_) {
    unsigned short* lb = &Asl[pi_][kh][0];
    #pragma unroll
    for (int i = 0; i < 2; ++i) {
      int c = i * 512 + tid;
      int rr = c >> 2, qq = c & 3;
      int k8 = qq ^ ((rr ^ (rr >> 2)) & 3);        // pre-swizzled global source
      gload16(A + (size_t)(tm + rr) * 1024 + j * 64 + kh * 32 + k8 * 8, lb + c * 8);
    }
  };
  auto stageB = [&](int j, int kh, int pi_) {
    unsigned short* lb = &Bsl[pi_][kh][0];
    #pragma unroll
    for (int i = 0; i < 2; ++i) {
      int c = i * 512 + tid;
      int rr = c >> 2, qq = c & 3;
      int k8 = qq ^ ((rr ^ (rr >> 2)) & 3);
      int row = tn + rr; if (row > V - 1) row = V - 1;   // clamp OOB vocab rows
      gload16(E + (size_t)row * 1024 + j * 64 + kh * 32 + k8 * 8, lb + c * 8);
    }
  };
  auto readA = [&](int kh, int pi_) {
    const unsigned short* ab = &Asl[pi_][kh][0];
    #pragma unroll
    for (int mi = 0; mi < 8; ++mi) {
      int rr = wm * 128 + mi * 16 + l16;
      af[mi] = *(const bf16x8*)(ab + rr * 32 + rchunk);
    }
  };

#define PHASE(khh, np, STAGE_STMT, WAIT_END)                                          \
  {                                                                                   \
    if ((np) == 0) readA(khh, pi);                                                    \
    const unsigned short* bb = &Bsl[pi][khh][0];                                      \
    bf16x8 b0 = *(const bf16x8*)(bb + (wn * 64 + ((np) + 0) * 16 + l16) * 32 + rchunk); \
    bf16x8 b1 = *(const bf16x8*)(bb + (wn * 64 + ((np) + 1) * 16 + l16) * 32 + rchunk); \
    STAGE_STMT;                                                                       \
    __builtin_amdgcn_s_barrier();                                                     \
    __builtin_amdgcn_s_setprio(1);                                                    \
    _Pragma("unroll")                                                                 \
    for (int mi = 0; mi < 8; ++mi) {                                                  \
      acc[mi][(np) + 0] = __builtin_amdgcn_mfma_f32_16x16x32_bf16(af[mi], b0, acc[mi][(np) + 0], 0, 0, 0); \
      acc[mi][(np) + 1] = __builtin_amdgcn_mfma_f32_16x16x32_bf16(af[mi], b1, acc[mi][(np) + 1], 0, 0, 0); \
    }                                                                                 \
    __builtin_amdgcn_s_setprio(0);                                                    \
    if (WAIT_END) asm volatile("s_waitcnt vmcnt(8)" ::: "memory");                    \
    __builtin_amdgcn_s_barrier();                                                     \
  }

  // prologue: 6 halves (tile0 complete + tile1 k-half0)
  stageA(0, 0, 0); stageB(0, 0, 0);
  stageA(0, 1, 0); stageB(0, 1, 0);
  stageA(1, 0, 1); stageB(1, 0, 1);
  asm volatile("s_waitcnt vmcnt(8)" ::: "memory");   // tile0 k-half0 landed
  __builtin_amdgcn_s_barrier();

  for (int t = 0; t < NT; ++t) {
    const int pi = t & 1;
    const int jn1 = (t + 1 < NT) ? t + 1 : NT - 1;   // clamped dummy stages keep
    const int jn2 = (t + 2 < NT) ? t + 2 : NT - 1;   // vmcnt arithmetic uniform
    PHASE(0, 0, stageA(jn1, 1, pi ^ 1), false);      // P0: kh0 n0-1, stage A1(t+1)
    PHASE(0, 2, stageB(jn1, 1, pi ^ 1), true);       // P1: kh0 n2-3, stage B1(t+1)
    PHASE(1, 0, stageA(jn2, 0, pi), false);          // P2: kh1 n0-1, stage A0(t+2)
    PHASE(1, 2, stageB(jn2, 0, pi), true);           // P3: kh1 n2-3, stage B0(t+2)
  }
  asm volatile("s_waitcnt vmcnt(0)" ::: "memory");
#undef PHASE

  #pragma unroll
  for (int mi = 0; mi < 8; ++mi) {
    #pragma unroll
    for (int rr = 0; rr < 4; ++rr) {
      int row = tm + wm * 128 + mi * 16 + lk * 4 + rr;  // 0..1535 padded
      int kk = row >> 9, bp = row & 511, b = bp >> 8, p = bp & 255;
      if (p >= PLEN) continue;
      size_t obase = ((size_t)((b * PLEN + p) * KD + kk)) * V;
      #pragma unroll
      for (int ni = 0; ni < 4; ++ni) {
        int col = tn + wn * 64 + ni * 16 + l16;
        if (col < V) Out[obase + col] = acc[mi][ni][rr];
      }
    }
  }
}

extern "C" void kernel_launch(void* const* d_in, const int* in_sizes, int n_in,
                              void* d_out, int out_size, void* d_ws, size_t ws_size,
                              hipStream_t stream)
{
  (void)in_sizes; (void)n_in; (void)out_size; (void)ws_size;
  const float* x      = (const float*)d_in[0];
  const float* embedw = (const float*)d_in[1];
  const float* rmsw   = (const float*)d_in[2];
  const float* projw  = (const float*)d_in[3];
  const float* projb  = (const float*)d_in[4];
  const float* ainw   = (const float*)d_in[5];
  const float* ainb   = (const float*)d_in[6];
  const float* aoutw  = (const float*)d_in[7];
  const float* aoutb  = (const float*)d_in[8];
  const float* ff1w   = (const float*)d_in[9];
  const float* ff1b   = (const float*)d_in[10];
  const float* ff2w   = (const float*)d_in[11];
  const float* ff2b   = (const float*)d_in[12];
  const float* ln1w   = (const float*)d_in[13];
  const float* ln1b   = (const float*)d_in[14];
  const float* ln2w   = (const float*)d_in[15];
  const float* ln2b   = (const float*)d_in[16];
  float* out = (float*)d_out;

  char* ws = (char*)d_ws;
  size_t off = 0;
  auto alloc = [&](size_t bytes) -> void* {
    void* ptr = ws + off;
    off = (off + bytes + 255) & ~(size_t)255;
    return ptr;
  };
  unsigned short* embed_b = (unsigned short*)alloc((size_t)V * D * 2);
  unsigned short* projw_b = (unsigned short*)alloc((size_t)KD * D * 2 * D * 2);
  unsigned short* ainw_b  = (unsigned short*)alloc((size_t)KD * 3 * D * D * 2);
  unsigned short* aoutw_b = (unsigned short*)alloc((size_t)KD * D * D * 2);
  unsigned short* ff1w_b  = (unsigned short*)alloc((size_t)KD * DFF * D * 2);
  unsigned short* ff2w_b  = (unsigned short*)alloc((size_t)KD * D * DFF * 2);
  float*          h_f     = (float*)alloc((size_t)MR * D * 4);
  unsigned short* h_all   = (unsigned short*)alloc((size_t)KD * MR * D * 2);
  unsigned short* merged  = (unsigned short*)alloc((size_t)MR * 2 * D * 2);
  float*          p_f     = (float*)alloc((size_t)MR * D * 4);
  unsigned short* p_b     = (unsigned short*)alloc((size_t)MR * D * 2);
  unsigned short* v_b     = (unsigned short*)alloc((size_t)MR * D * 2);
  float*          sa_f    = (float*)alloc((size_t)MR * D * 4);
  float*          s1_f    = (float*)alloc((size_t)MR * D * 4);
  unsigned short* s1_b    = (unsigned short*)alloc((size_t)MR * D * 2);
  unsigned short* ff_b    = (unsigned short*)alloc((size_t)MR * DFF * 2);
  float*          ff2_f   = (float*)alloc((size_t)MR * D * 4);

  auto cvt = [&](const float* s, unsigned short* dgt, long n) {
    long n4 = n / 4;
    int blocks = (int)((n4 + 255) / 256);
    if (blocks > 4096) blocks = 4096;
    cvt_bf16<<<dim3(blocks), dim3(256), 0, stream>>>(s, dgt, (int)n);
  };
  cvt(embedw, embed_b, (long)V * D);
  cvt(projw,  projw_b, (long)KD * D * 2 * D);
  cvt(ainw,   ainw_b,  (long)KD * 3 * D * D);
  cvt(aoutw,  aoutw_b, (long)KD * D * D);
  cvt(ff1w,   ff1w_b,  (long)KD * DFF * D);
  cvt(ff2w,   ff2w_b,  (long)KD * D * DFF);

  init_h<<<dim3(MR), dim3(256), 0, stream>>>(x, h_f);

  for (int k = 0; k < KD; ++k) {
    rms_merge<<<dim3(MR), dim3(256), 0, stream>>>(h_f, x, rmsw, merged, k);
    gemm_bt<2,2,64,true,false,true,true><<<dim3(D/64, MR/64), dim3(256), 0, stream>>>(
        merged, projw_b + (size_t)k * D * 2 * D, projb + (size_t)k * D, p_f, p_b, MR, D, 2 * D);
    gemm_bt<2,2,64,true,false,false,true><<<dim3(D/64, MR/64), dim3(256), 0, stream>>>(
        p_b, ainw_b + (size_t)k * 3 * D * D + (size_t)2 * D * D, ainb + (size_t)k * 3 * D + 2 * D,
        (float*)nullptr, v_b, MR, D, D);
    gemm_bt<2,2,64,true,false,true,false><<<dim3(D/64, MR/64), dim3(256), 0, stream>>>(
        v_b, aoutw_b + (size_t)k * D * D, aoutb + (size_t)k * D, sa_f, (unsigned short*)nullptr, MR, D, D);
    add_ln<<<dim3(MR), dim3(256), 0, stream>>>(p_f, sa_f, ln1w + (size_t)k * D, ln1b + (size_t)k * D, s1_f, s1_b);
    gemm_bt<2,2,64,true,true,false,true><<<dim3(DFF/64, MR/64), dim3(256), 0, stream>>>(
        s1_b, ff1w_b + (size_t)k * DFF * D, ff1b + (size_t)k * DFF, (float*)nullptr, ff_b, MR, DFF, D);
    gemm_bt<2,2,64,true,false,true,false><<<dim3(D/64, MR/64), dim3(256), 0, stream>>>(
        ff_b, ff2w_b + (size_t)k * D * DFF, ff2b + (size_t)k * D, ff2_f, (unsigned short*)nullptr, MR, D, DFF);
    add_ln<<<dim3(MR), dim3(256), 0, stream>>>(s1_f, ff2_f, ln2w + (size_t)k * D, ln2b + (size_t)k * D,
                                               h_f, h_all + (size_t)k * MR * D);
  }

  // logits for all 3 depths: (1536 x 1024) @ (50257 x 1024)^T, 8-phase 256^2 pipeline
  gemm_logits8<<<dim3(6 * 197), dim3(512), 0, stream>>>(h_all, embed_b, out);
}

// Round 3
// 643.838 us; speedup vs baseline: 1.1688x; 1.0182x over previous
//
#include <hip/hip_runtime.h>
#include <stdint.h>

#define DEV __device__ __forceinline__

using bf16x8 = __attribute__((ext_vector_type(8))) __bf16;
using f32x4  = __attribute__((ext_vector_type(4))) float;

static constexpr int D    = 1024;
static constexpr int V    = 50257;
static constexpr int DFF  = 2048;
static constexpr int KD   = 3;     // depth
static constexpr int MR   = 512;   // padded rows per depth: r = b*256 + p
static constexpr int PLEN = 253;

DEV unsigned short f2b(float f) {
  unsigned int u = __float_as_uint(f);
  u += 0x7fffu + ((u >> 16) & 1u);   // RNE
  return (unsigned short)(u >> 16);
}

DEV void gload16(const void* g, void* l) {
  __builtin_amdgcn_global_load_lds(
      (const __attribute__((address_space(1))) unsigned int*)g,
      (__attribute__((address_space(3))) unsigned int*)l, 16, 0, 0);
}

// ---------- f32 -> bf16 bulk convert (n multiple of 4) ----------
__global__ void cvt_bf16(const float* __restrict__ src, unsigned short* __restrict__ dst, int n) {
  int i = blockIdx.x * blockDim.x + threadIdx.x;
  int stride = gridDim.x * blockDim.x;
  for (int j = i; j * 4 < n; j += stride) {
    float4 v = *(const float4*)(src + (size_t)j * 4);
    ushort4 o;
    o.x = f2b(v.x); o.y = f2b(v.y); o.z = f2b(v.z); o.w = f2b(v.w);
    *(ushort4*)(dst + (size_t)j * 4) = o;
  }
}

// ---------- h0 = x[:, :253] into padded 512-row layout ----------
__global__ __launch_bounds__(256) void init_h(const float* __restrict__ x, float* __restrict__ h) {
  int r = blockIdx.x, tid = threadIdx.x;
  int b = r >> 8, p = r & 255;
  float4 v = {0.f, 0.f, 0.f, 0.f};
  if (p < PLEN) v = *(const float4*)(x + ((size_t)(b * 256 + p)) * D + tid * 4);
  *(float4*)(h + (size_t)r * D + tid * 4) = v;
}

// ---------- merged = [rms(h), rms(e_k)] in bf16, one block per padded row ----------
__global__ __launch_bounds__(256) void rms_merge(
    const float* __restrict__ h, const float* __restrict__ x,
    const float* __restrict__ rw, unsigned short* __restrict__ merged, int koff)
{
  int r = blockIdx.x, tid = threadIdx.x;
  int b = r >> 8, p = r & 255;
  bool valid = p < PLEN;
  float4 hv = {0,0,0,0}, ev = {0,0,0,0};
  if (valid) {
    hv = *(const float4*)(h + (size_t)r * D + tid * 4);
    ev = *(const float4*)(x + ((size_t)(b * 256 + p + koff + 1)) * D + tid * 4);
  }
  float sh = hv.x*hv.x + hv.y*hv.y + hv.z*hv.z + hv.w*hv.w;
  float se = ev.x*ev.x + ev.y*ev.y + ev.z*ev.z + ev.w*ev.w;
  #pragma unroll
  for (int o = 32; o > 0; o >>= 1) { sh += __shfl_down(sh, o, 64); se += __shfl_down(se, o, 64); }
  __shared__ float ssh[4], sse[4];
  if ((tid & 63) == 0) { ssh[tid >> 6] = sh; sse[tid >> 6] = se; }
  __syncthreads();
  sh = ssh[0] + ssh[1] + ssh[2] + ssh[3];
  se = sse[0] + sse[1] + sse[2] + sse[3];
  float sc_h = rsqrtf(sh * (1.0f / D) + 1e-6f);
  float sc_e = rsqrtf(se * (1.0f / D) + 1e-6f);
  float4 wv = *(const float4*)(rw + tid * 4);
  ushort4 oh, oe;
  oh.x = f2b(hv.x * sc_h * wv.x); oh.y = f2b(hv.y * sc_h * wv.y);
  oh.z = f2b(hv.z * sc_h * wv.z); oh.w = f2b(hv.w * sc_h * wv.w);
  oe.x = f2b(ev.x * sc_e * wv.x); oe.y = f2b(ev.y * sc_e * wv.y);
  oe.z = f2b(ev.z * sc_e * wv.z); oe.w = f2b(ev.w * sc_e * wv.w);
  unsigned short* mrow = merged + (size_t)r * (2 * D);
  *(ushort4*)(mrow + tid * 4) = oh;
  *(ushort4*)(mrow + D + tid * 4) = oe;
}

// ---------- out = LayerNorm(ia + ib) * w + b ; writes f32 and bf16 ----------
__global__ __launch_bounds__(256) void add_ln(
    const float* __restrict__ ia, const float* __restrict__ ib,
    const float* __restrict__ w, const float* __restrict__ bb,
    float* __restrict__ of, unsigned short* __restrict__ ob)
{
  int r = blockIdx.x, tid = threadIdx.x;
  float4 va = *(const float4*)(ia + (size_t)r * D + tid * 4);
  float4 vb = *(const float4*)(ib + (size_t)r * D + tid * 4);
  float4 v = {va.x+vb.x, va.y+vb.y, va.z+vb.z, va.w+vb.w};
  float s  = v.x + v.y + v.z + v.w;
  float s2 = v.x*v.x + v.y*v.y + v.z*v.z + v.w*v.w;
  #pragma unroll
  for (int o = 32; o > 0; o >>= 1) { s += __shfl_down(s, o, 64); s2 += __shfl_down(s2, o, 64); }
  __shared__ float rs[4], rq[4];
  if ((tid & 63) == 0) { rs[tid >> 6] = s; rq[tid >> 6] = s2; }
  __syncthreads();
  s  = rs[0] + rs[1] + rs[2] + rs[3];
  s2 = rq[0] + rq[1] + rq[2] + rq[3];
  float m   = s * (1.0f / D);
  float var = s2 * (1.0f / D) - m * m;
  float sc  = rsqrtf(var + 1e-5f);
  float4 wv = *(const float4*)(w + tid * 4);
  float4 bv = *(const float4*)(bb + tid * 4);
  float4 o;
  o.x = (v.x - m) * sc * wv.x + bv.x;
  o.y = (v.y - m) * sc * wv.y + bv.y;
  o.z = (v.z - m) * sc * wv.z + bv.z;
  o.w = (v.w - m) * sc * wv.w + bv.w;
  *(float4*)(of + (size_t)r * D + tid * 4) = o;
  ushort4 ub; ub.x = f2b(o.x); ub.y = f2b(o.y); ub.z = f2b(o.z); ub.w = f2b(o.w);
  *(ushort4*)(ob + (size_t)r * D + tid * 4) = ub;
}

// ---------- trunk GEMM: C = A @ Bt^T (+bias), 64x64 tile, BK=64, 3-deep counted vmcnt ----------
// A: M x K row-major bf16, Bt: N x K row-major bf16. 4 waves (2x2), per-wave 32x32.
// LDS rows are 128B (64 bf16); chunk-XOR swizzle (chunk ^= row&7) => conflict-free b128 reads.
template<bool BIAS, bool RELU, bool OF32, bool OB16>
__global__ __launch_bounds__(256) void gemm2(
    const unsigned short* __restrict__ A, const unsigned short* __restrict__ Bt,
    const float* __restrict__ bias, float* __restrict__ Cf,
    unsigned short* __restrict__ Cb, int N, int K)
{
  constexpr int BK = 64;
  __shared__ __align__(16) unsigned short As[3][64 * BK];
  __shared__ __align__(16) unsigned short Bs[3][64 * BK];
  const int tid = threadIdx.x;
  const int lane = tid & 63, wave = tid >> 6;
  const int wm = wave >> 1, wn = wave & 1;
  const int l16 = lane & 15, lk = lane >> 4;
  const int tm = blockIdx.y * 64, tn = blockIdx.x * 64;
  const int NT = K / BK;

  auto stage = [&](int t, int s) {
    #pragma unroll
    for (int i = 0; i < 2; ++i) {
      int c = i * 256 + tid;                 // 512 chunks of 16B = 8KB
      int rr = c >> 3, qq = c & 7;
      int k8 = qq ^ (rr & 7);
      gload16(A + (size_t)(tm + rr) * K + t * BK + k8 * 8, &As[s][c * 8]);
    }
    #pragma unroll
    for (int i = 0; i < 2; ++i) {
      int c = i * 256 + tid;
      int rr = c >> 3, qq = c & 7;
      int k8 = qq ^ (rr & 7);
      gload16(Bt + (size_t)(tn + rr) * K + t * BK + k8 * 8, &Bs[s][c * 8]);
    }
  };

  f32x4 acc[2][2] = {};
  stage(0, 0);
  stage(1, 1);
  for (int t = 0; t < NT; ++t) {
    int t2 = (t + 2 < NT) ? t + 2 : NT - 1;  // dummy tail keeps vmcnt arithmetic uniform
    stage(t2, (t + 2) % 3);
    asm volatile("s_waitcnt vmcnt(8)" ::: "memory");   // step-t data landed (2 stages in flight)
    __builtin_amdgcn_s_barrier();
    const unsigned short* as = &As[t % 3][0];
    const unsigned short* bs = &Bs[t % 3][0];
    #pragma unroll
    for (int kk = 0; kk < 2; ++kk) {
      bf16x8 af[2], bg[2];
      #pragma unroll
      for (int mi = 0; mi < 2; ++mi) {
        int row = wm * 32 + mi * 16 + l16;
        int ch = (kk * 4 + lk) ^ (row & 7);
        af[mi] = *(const bf16x8*)(as + row * 64 + ch * 8);
      }
      #pragma unroll
      for (int ni = 0; ni < 2; ++ni) {
        int row = wn * 32 + ni * 16 + l16;
        int ch = (kk * 4 + lk) ^ (row & 7);
        bg[ni] = *(const bf16x8*)(bs + row * 64 + ch * 8);
      }
      #pragma unroll
      for (int mi = 0; mi < 2; ++mi)
        #pragma unroll
        for (int ni = 0; ni < 2; ++ni)
          acc[mi][ni] = __builtin_amdgcn_mfma_f32_16x16x32_bf16(af[mi], bg[ni], acc[mi][ni], 0, 0, 0);
    }
    __builtin_amdgcn_s_barrier();
  }
  asm volatile("s_waitcnt vmcnt(0)" ::: "memory");     // drain dummies before endpgm

  const int rbase = tm + wm * 32, cbase = tn + wn * 32;
  #pragma unroll
  for (int ni = 0; ni < 2; ++ni) {
    int col = cbase + ni * 16 + l16;
    float bvv = BIAS ? bias[col] : 0.0f;
    #pragma unroll
    for (int mi = 0; mi < 2; ++mi) {
      #pragma unroll
      for (int rr = 0; rr < 4; ++rr) {
        int row = rbase + mi * 16 + lk * 4 + rr;
        float v = acc[mi][ni][rr] + bvv;
        if (RELU) v = fmaxf(v, 0.0f);
        size_t idx = (size_t)row * N + col;
        if (OF32) Cf[idx] = v;
        if (OB16) Cb[idx] = f2b(v);
      }
    }
  }
}

// ---------- logits: BM=512 x BN=128, BK=32, 8 waves (4Mx2N), 3-deep counted vmcnt ----------
// B-traffic (embed) = 3 x 103MB (vs 6x at BM=256); A (3MB) is L2-resident.
// LDS: 3 slots x (A 32KB + B 8KB) = 120KB. Lead = 2 K-steps >> HBM latency.
__global__ __launch_bounds__(512, 2) void gemm_logits5(
    const unsigned short* __restrict__ A, const unsigned short* __restrict__ E,
    float* __restrict__ Out)
{
  constexpr int NT  = 32;            // K=1024 / BK=32
  constexpr int NWG = 3 * 393;       // M-tiles x N-tiles
  __shared__ __align__(16) unsigned short Asl[3][512 * 32];
  __shared__ __align__(16) unsigned short Bsl[3][128 * 32];

  const int tid  = threadIdx.x;
  const int lane = tid & 63, wave = tid >> 6;
  const int wm = wave >> 1, wn = wave & 1;       // 4M x 2N
  const int l16 = lane & 15, lk = lane >> 4;
  const int rchunk = ((lk ^ ((l16 ^ (l16 >> 2)) & 3)) & 3) * 8;  // swizzled 16B chunk (ushorts)

  // bijective XCD swizzle (m204): nwg = 1179 = 8*147 + 3
  int orig = blockIdx.x;
  int xcd = orig & 7, local = orig >> 3;
  constexpr int q = NWG / 8, r8 = NWG % 8;
  int wgid = (xcd < r8 ? xcd * (q + 1) : r8 * (q + 1) + (xcd - r8) * q) + local;
  const int tm = (wgid % 3) * 512;   // 3 consecutive wgid share the same B panel
  const int tn = (wgid / 3) * 128;

  f32x4 acc[8][4] = {};

  auto stageA = [&](int t, int s) {
    unsigned short* lb = &Asl[s][0];
    #pragma unroll
    for (int i = 0; i < 4; ++i) {
      int c = i * 512 + tid;                   // 2048 chunks = 32KB
      int rr = c >> 2, qq = c & 3;
      int k8 = qq ^ ((rr ^ (rr >> 2)) & 3);
      gload16(A + (size_t)(tm + rr) * 1024 + t * 32 + k8 * 8, lb + c * 8);
    }
  };
  auto stageB = [&](int t, int s) {
    unsigned short* lb = &Bsl[s][0];
    int c = tid;                               // 512 chunks = 8KB
    int rr = c >> 2, qq = c & 3;
    int k8 = qq ^ ((rr ^ (rr >> 2)) & 3);
    int row = tn + rr; if (row > V - 1) row = V - 1;   // clamp OOB vocab rows
    gload16(E + (size_t)row * 1024 + t * 32 + k8 * 8, lb + c * 8);
  };

  // prologue: 2 steps in flight (10 VMEM instrs per wave)
  stageA(0, 0); stageB(0, 0);
  stageA(1, 1); stageB(1, 1);

  for (int t = 0; t < NT; ++t) {
    int t2 = (t + 2 < NT) ? t + 2 : NT - 1;    // dummy tail keeps vmcnt uniform
    stageA(t2, (t + 2) % 3);
    stageB(t2, (t + 2) % 3);
    asm volatile("s_waitcnt vmcnt(10)" ::: "memory");  // step-t landed (2 steps x 5 instr allowed)
    __builtin_amdgcn_s_barrier();

    const unsigned short* as = &Asl[t % 3][0];
    const unsigned short* bs = &Bsl[t % 3][0];
    bf16x8 af[8], bg[4];
    #pragma unroll
    for (int mi = 0; mi < 8; ++mi)
      af[mi] = *(const bf16x8*)(as + (wm * 128 + mi * 16 + l16) * 32 + rchunk);
    #pragma unroll
    for (int ni = 0; ni < 4; ++ni)
      bg[ni] = *(const bf16x8*)(bs + (wn * 64 + ni * 16 + l16) * 32 + rchunk);

    __builtin_amdgcn_s_setprio(1);
    #pragma unroll
    for (int mi = 0; mi < 8; ++mi)
      #pragma unroll
      for (int ni = 0; ni < 4; ++ni)
        acc[mi][ni] = __builtin_amdgcn_mfma_f32_16x16x32_bf16(af[mi], bg[ni], acc[mi][ni], 0, 0, 0);
    __builtin_amdgcn_s_setprio(0);
    __builtin_amdgcn_s_barrier();
  }
  asm volatile("s_waitcnt vmcnt(0)" ::: "memory");     // drain dummies before stores/endpgm

  #pragma unroll
  for (int mi = 0; mi < 8; ++mi) {
    #pragma unroll
    for (int rr = 0; rr < 4; ++rr) {
      int row = tm + wm * 128 + mi * 16 + lk * 4 + rr;  // 0..1535 padded
      int kk = row >> 9, bp = row & 511, b = bp >> 8, p = bp & 255;
      if (p >= PLEN) continue;
      size_t obase = ((size_t)((b * PLEN + p) * KD + kk)) * V;
      #pragma unroll
      for (int ni = 0; ni < 4; ++ni) {
        int col = tn + wn * 64 + ni * 16 + l16;
        if (col < V) Out[obase + col] = acc[mi][ni][rr];
      }
    }
  }
}

extern "C" void kernel_launch(void* const* d_in, const int* in_sizes, int n_in,
                              void* d_out, int out_size, void* d_ws, size_t ws_size,
                              hipStream_t stream)
{
  (void)in_sizes; (void)n_in; (void)out_size; (void)ws_size;
  const float* x      = (const float*)d_in[0];
  const float* embedw = (const float*)d_in[1];
  const float* rmsw   = (const float*)d_in[2];
  const float* projw  = (const float*)d_in[3];
  const float* projb  = (const float*)d_in[4];
  const float* ainw   = (const float*)d_in[5];
  const float* ainb   = (const float*)d_in[6];
  const float* aoutw  = (const float*)d_in[7];
  const float* aoutb  = (const float*)d_in[8];
  const float* ff1w   = (const float*)d_in[9];
  const float* ff1b   = (const float*)d_in[10];
  const float* ff2w   = (const float*)d_in[11];
  const float* ff2b   = (const float*)d_in[12];
  const float* ln1w   = (const float*)d_in[13];
  const float* ln1b   = (const float*)d_in[14];
  const float* ln2w   = (const float*)d_in[15];
  const float* ln2b   = (const float*)d_in[16];
  float* out = (float*)d_out;

  char* ws = (char*)d_ws;
  size_t off = 0;
  auto alloc = [&](size_t bytes) -> void* {
    void* ptr = ws + off;
    off = (off + bytes + 255) & ~(size_t)255;
    return ptr;
  };
  unsigned short* embed_b = (unsigned short*)alloc((size_t)V * D * 2);
  unsigned short* projw_b = (unsigned short*)alloc((size_t)KD * D * 2 * D * 2);
  unsigned short* ainw_b  = (unsigned short*)alloc((size_t)KD * 3 * D * D * 2);
  unsigned short* aoutw_b = (unsigned short*)alloc((size_t)KD * D * D * 2);
  unsigned short* ff1w_b  = (unsigned short*)alloc((size_t)KD * DFF * D * 2);
  unsigned short* ff2w_b  = (unsigned short*)alloc((size_t)KD * D * DFF * 2);
  float*          h_f     = (float*)alloc((size_t)MR * D * 4);
  unsigned short* h_all   = (unsigned short*)alloc((size_t)KD * MR * D * 2);
  unsigned short* merged  = (unsigned short*)alloc((size_t)MR * 2 * D * 2);
  float*          p_f     = (float*)alloc((size_t)MR * D * 4);
  unsigned short* p_b     = (unsigned short*)alloc((size_t)MR * D * 2);
  unsigned short* v_b     = (unsigned short*)alloc((size_t)MR * D * 2);
  float*          sa_f    = (float*)alloc((size_t)MR * D * 4);
  float*          s1_f    = (float*)alloc((size_t)MR * D * 4);
  unsigned short* s1_b    = (unsigned short*)alloc((size_t)MR * D * 2);
  unsigned short* ff_b    = (unsigned short*)alloc((size_t)MR * DFF * 2);
  float*          ff2_f   = (float*)alloc((size_t)MR * D * 4);

  auto cvt = [&](const float* s, unsigned short* dgt, long n) {
    long n4 = n / 4;
    int blocks = (int)((n4 + 255) / 256);
    if (blocks > 4096) blocks = 4096;
    cvt_bf16<<<dim3(blocks), dim3(256), 0, stream>>>(s, dgt, (int)n);
  };
  cvt(embedw, embed_b, (long)V * D);
  cvt(projw,  projw_b, (long)KD * D * 2 * D);
  cvt(ainw,   ainw_b,  (long)KD * 3 * D * D);
  cvt(aoutw,  aoutw_b, (long)KD * D * D);
  cvt(ff1w,   ff1w_b,  (long)KD * DFF * D);
  cvt(ff2w,   ff2w_b,  (long)KD * D * DFF);

  init_h<<<dim3(MR), dim3(256), 0, stream>>>(x, h_f);

  for (int k = 0; k < KD; ++k) {
    rms_merge<<<dim3(MR), dim3(256), 0, stream>>>(h_f, x, rmsw, merged, k);
    // p = merged @ proj_w[k]^T + proj_b[k]   (M=512, N=1024, K=2048)
    gemm2<true,false,true,true><<<dim3(D/64, MR/64), dim3(256), 0, stream>>>(
        merged, projw_b + (size_t)k * D * 2 * D, projb + (size_t)k * D, p_f, p_b, D, 2 * D);
    // v = p @ wv^T + bv  (wv = attn_in_w[k][2D:], 1024x1024)
    gemm2<true,false,false,true><<<dim3(D/64, MR/64), dim3(256), 0, stream>>>(
        p_b, ainw_b + (size_t)k * 3 * D * D + (size_t)2 * D * D, ainb + (size_t)k * 3 * D + 2 * D,
        (float*)nullptr, v_b, D, D);
    // sa = v @ attn_out_w[k]^T + b
    gemm2<true,false,true,false><<<dim3(D/64, MR/64), dim3(256), 0, stream>>>(
        v_b, aoutw_b + (size_t)k * D * D, aoutb + (size_t)k * D, sa_f, (unsigned short*)nullptr, D, D);
    // s1 = LN(p + sa)
    add_ln<<<dim3(MR), dim3(256), 0, stream>>>(p_f, sa_f, ln1w + (size_t)k * D, ln1b + (size_t)k * D, s1_f, s1_b);
    // ff = relu(s1 @ ff1_w[k]^T + b)   (N=2048)
    gemm2<true,true,false,true><<<dim3(DFF/64, MR/64), dim3(256), 0, stream>>>(
        s1_b, ff1w_b + (size_t)k * DFF * D, ff1b + (size_t)k * DFF, (float*)nullptr, ff_b, DFF, D);
    // ff2 = ff @ ff2_w[k]^T + b        (K=2048)
    gemm2<true,false,true,false><<<dim3(D/64, MR/64), dim3(256), 0, stream>>>(
        ff_b, ff2w_b + (size_t)k * D * DFF, ff2b + (size_t)k * D, ff2_f, (unsigned short*)nullptr, D, 2 * D);
    // h = LN(s1 + ff2) -> h_f (f32, next iter) + h_all[k] (bf16, logits)
    add_ln<<<dim3(MR), dim3(256), 0, stream>>>(s1_f, ff2_f, ln2w + (size_t)k * D, ln2b + (size_t)k * D,
                                               h_f, h_all + (size_t)k * MR * D);
  }

  // logits for all 3 depths: (1536 x 1024) @ (50257 x 1024)^T, BM=512 pipeline
  gemm_logits5<<<dim3(3 * 393), dim3(512), 0, stream>>>(h_all, embed_b, out);
}

// Round 4
// 637.825 us; speedup vs baseline: 1.1798x; 1.0094x over previous
//
#include <hip/hip_runtime.h>
#include <stdint.h>

#define DEV __device__ __forceinline__

using bf16x8 = __attribute__((ext_vector_type(8))) __bf16;
using f32x4  = __attribute__((ext_vector_type(4))) float;

static constexpr int D    = 1024;
static constexpr int V    = 50257;
static constexpr int DFF  = 2048;
static constexpr int KD   = 3;     // depth
static constexpr int MR   = 512;   // padded rows per depth: r = b*256 + p
static constexpr int PLEN = 253;

DEV unsigned short f2b(float f) {
  unsigned int u = __float_as_uint(f);
  u += 0x7fffu + ((u >> 16) & 1u);   // RNE
  return (unsigned short)(u >> 16);
}

DEV void gload16(const void* g, void* l) {
  __builtin_amdgcn_global_load_lds(
      (const __attribute__((address_space(1))) unsigned int*)g,
      (__attribute__((address_space(3))) unsigned int*)l, 16, 0, 0);
}

// ---------- f32 -> bf16 bulk convert (n multiple of 4) ----------
__global__ void cvt_bf16(const float* __restrict__ src, unsigned short* __restrict__ dst, int n) {
  int i = blockIdx.x * blockDim.x + threadIdx.x;
  int stride = gridDim.x * blockDim.x;
  for (int j = i; j * 4 < n; j += stride) {
    float4 v = *(const float4*)(src + (size_t)j * 4);
    ushort4 o;
    o.x = f2b(v.x); o.y = f2b(v.y); o.z = f2b(v.z); o.w = f2b(v.w);
    *(ushort4*)(dst + (size_t)j * 4) = o;
  }
}

// ---------- h0 = x[:, :253] into padded 512-row layout ----------
__global__ __launch_bounds__(256) void init_h(const float* __restrict__ x, float* __restrict__ h) {
  int r = blockIdx.x, tid = threadIdx.x;
  int b = r >> 8, p = r & 255;
  float4 v = {0.f, 0.f, 0.f, 0.f};
  if (p < PLEN) v = *(const float4*)(x + ((size_t)(b * 256 + p)) * D + tid * 4);
  *(float4*)(h + (size_t)r * D + tid * 4) = v;
}

// ---------- merged = [rms(h), rms(e_k)] in bf16, one block per padded row ----------
__global__ __launch_bounds__(256) void rms_merge(
    const float* __restrict__ h, const float* __restrict__ x,
    const float* __restrict__ rw, unsigned short* __restrict__ merged, int koff)
{
  int r = blockIdx.x, tid = threadIdx.x;
  int b = r >> 8, p = r & 255;
  bool valid = p < PLEN;
  float4 hv = {0,0,0,0}, ev = {0,0,0,0};
  if (valid) {
    hv = *(const float4*)(h + (size_t)r * D + tid * 4);
    ev = *(const float4*)(x + ((size_t)(b * 256 + p + koff + 1)) * D + tid * 4);
  }
  float sh = hv.x*hv.x + hv.y*hv.y + hv.z*hv.z + hv.w*hv.w;
  float se = ev.x*ev.x + ev.y*ev.y + ev.z*ev.z + ev.w*ev.w;
  #pragma unroll
  for (int o = 32; o > 0; o >>= 1) { sh += __shfl_down(sh, o, 64); se += __shfl_down(se, o, 64); }
  __shared__ float ssh[4], sse[4];
  if ((tid & 63) == 0) { ssh[tid >> 6] = sh; sse[tid >> 6] = se; }
  __syncthreads();
  sh = ssh[0] + ssh[1] + ssh[2] + ssh[3];
  se = sse[0] + sse[1] + sse[2] + sse[3];
  float sc_h = rsqrtf(sh * (1.0f / D) + 1e-6f);
  float sc_e = rsqrtf(se * (1.0f / D) + 1e-6f);
  float4 wv = *(const float4*)(rw + tid * 4);
  ushort4 oh, oe;
  oh.x = f2b(hv.x * sc_h * wv.x); oh.y = f2b(hv.y * sc_h * wv.y);
  oh.z = f2b(hv.z * sc_h * wv.z); oh.w = f2b(hv.w * sc_h * wv.w);
  oe.x = f2b(ev.x * sc_e * wv.x); oe.y = f2b(ev.y * sc_e * wv.y);
  oe.z = f2b(ev.z * sc_e * wv.z); oe.w = f2b(ev.w * sc_e * wv.w);
  unsigned short* mrow = merged + (size_t)r * (2 * D);
  *(ushort4*)(mrow + tid * 4) = oh;
  *(ushort4*)(mrow + D + tid * 4) = oe;
}

// ---------- out = LayerNorm(ia + ib) * w + b ; writes f32 and bf16 ----------
__global__ __launch_bounds__(256) void add_ln(
    const float* __restrict__ ia, const float* __restrict__ ib,
    const float* __restrict__ w, const float* __restrict__ bb,
    float* __restrict__ of, unsigned short* __restrict__ ob)
{
  int r = blockIdx.x, tid = threadIdx.x;
  float4 va = *(const float4*)(ia + (size_t)r * D + tid * 4);
  float4 vb = *(const float4*)(ib + (size_t)r * D + tid * 4);
  float4 v = {va.x+vb.x, va.y+vb.y, va.z+vb.z, va.w+vb.w};
  float s  = v.x + v.y + v.z + v.w;
  float s2 = v.x*v.x + v.y*v.y + v.z*v.z + v.w*v.w;
  #pragma unroll
  for (int o = 32; o > 0; o >>= 1) { s += __shfl_down(s, o, 64); s2 += __shfl_down(s2, o, 64); }
  __shared__ float rs[4], rq[4];
  if ((tid & 63) == 0) { rs[tid >> 6] = s; rq[tid >> 6] = s2; }
  __syncthreads();
  s  = rs[0] + rs[1] + rs[2] + rs[3];
  s2 = rq[0] + rq[1] + rq[2] + rq[3];
  float m   = s * (1.0f / D);
  float var = s2 * (1.0f / D) - m * m;
  float sc  = rsqrtf(var + 1e-5f);
  float4 wv = *(const float4*)(w + tid * 4);
  float4 bv = *(const float4*)(bb + tid * 4);
  float4 o;
  o.x = (v.x - m) * sc * wv.x + bv.x;
  o.y = (v.y - m) * sc * wv.y + bv.y;
  o.z = (v.z - m) * sc * wv.z + bv.z;
  o.w = (v.w - m) * sc * wv.w + bv.w;
  *(float4*)(of + (size_t)r * D + tid * 4) = o;
  ushort4 ub; ub.x = f2b(o.x); ub.y = f2b(o.y); ub.z = f2b(o.z); ub.w = f2b(o.w);
  *(ushort4*)(ob + (size_t)r * D + tid * 4) = ub;
}

// ---------- trunk GEMM: C = A @ Bt^T (+bias), 64x64 tile, BK=64, 3-deep counted vmcnt ----------
template<bool BIAS, bool RELU, bool OF32, bool OB16>
__global__ __launch_bounds__(256) void gemm2(
    const unsigned short* __restrict__ A, const unsigned short* __restrict__ Bt,
    const float* __restrict__ bias, float* __restrict__ Cf,
    unsigned short* __restrict__ Cb, int N, int K)
{
  constexpr int BK = 64;
  __shared__ __align__(16) unsigned short As[3][64 * BK];
  __shared__ __align__(16) unsigned short Bs[3][64 * BK];
  const int tid = threadIdx.x;
  const int lane = tid & 63, wave = tid >> 6;
  const int wm = wave >> 1, wn = wave & 1;
  const int l16 = lane & 15, lk = lane >> 4;
  const int tm = blockIdx.y * 64, tn = blockIdx.x * 64;
  const int NT = K / BK;

  auto stage = [&](int t, int s) {
    #pragma unroll
    for (int i = 0; i < 2; ++i) {
      int c = i * 256 + tid;
      int rr = c >> 3, qq = c & 7;
      int k8 = qq ^ (rr & 7);
      gload16(A + (size_t)(tm + rr) * K + t * BK + k8 * 8, &As[s][c * 8]);
    }
    #pragma unroll
    for (int i = 0; i < 2; ++i) {
      int c = i * 256 + tid;
      int rr = c >> 3, qq = c & 7;
      int k8 = qq ^ (rr & 7);
      gload16(Bt + (size_t)(tn + rr) * K + t * BK + k8 * 8, &Bs[s][c * 8]);
    }
  };

  f32x4 acc[2][2] = {};
  stage(0, 0);
  stage(1, 1);
  for (int t = 0; t < NT; ++t) {
    int t2 = (t + 2 < NT) ? t + 2 : NT - 1;
    stage(t2, (t + 2) % 3);
    asm volatile("s_waitcnt vmcnt(8)" ::: "memory");
    __builtin_amdgcn_s_barrier();
    const unsigned short* as = &As[t % 3][0];
    const unsigned short* bs = &Bs[t % 3][0];
    #pragma unroll
    for (int kk = 0; kk < 2; ++kk) {
      bf16x8 af[2], bg[2];
      #pragma unroll
      for (int mi = 0; mi < 2; ++mi) {
        int row = wm * 32 + mi * 16 + l16;
        int ch = (kk * 4 + lk) ^ (row & 7);
        af[mi] = *(const bf16x8*)(as + row * 64 + ch * 8);
      }
      #pragma unroll
      for (int ni = 0; ni < 2; ++ni) {
        int row = wn * 32 + ni * 16 + l16;
        int ch = (kk * 4 + lk) ^ (row & 7);
        bg[ni] = *(const bf16x8*)(bs + row * 64 + ch * 8);
      }
      #pragma unroll
      for (int mi = 0; mi < 2; ++mi)
        #pragma unroll
        for (int ni = 0; ni < 2; ++ni)
          acc[mi][ni] = __builtin_amdgcn_mfma_f32_16x16x32_bf16(af[mi], bg[ni], acc[mi][ni], 0, 0, 0);
    }
    __builtin_amdgcn_s_barrier();
  }
  asm volatile("s_waitcnt vmcnt(0)" ::: "memory");

  const int rbase = tm + wm * 32, cbase = tn + wn * 32;
  #pragma unroll
  for (int ni = 0; ni < 2; ++ni) {
    int col = cbase + ni * 16 + l16;
    float bvv = BIAS ? bias[col] : 0.0f;
    #pragma unroll
    for (int mi = 0; mi < 2; ++mi) {
      #pragma unroll
      for (int rr = 0; rr < 4; ++rr) {
        int row = rbase + mi * 16 + lk * 4 + rr;
        float v = acc[mi][ni][rr] + bvv;
        if (RELU) v = fmaxf(v, 0.0f);
        size_t idx = (size_t)row * N + col;
        if (OF32) Cf[idx] = v;
        if (OB16) Cb[idx] = f2b(v);
      }
    }
  }
}

// ---------- logits: BM=512 x BN=128, BK=32, 8 waves (4Mx2N), 2-deep, 2 blocks/CU ----------
// 80KB LDS/block -> 2 blocks/CU (16 waves/CU): one block's vmcnt stall is hidden by the
// other block's MFMA burst (m97's cross-block TLP). Lead = 1 K-step, vmcnt(5).
__global__ __launch_bounds__(512, 2) void gemm_logits5(
    const unsigned short* __restrict__ A, const unsigned short* __restrict__ E,
    float* __restrict__ Out)
{
  constexpr int NT  = 32;            // K=1024 / BK=32
  constexpr int NWG = 3 * 393;       // M-tiles x N-tiles
  __shared__ __align__(16) unsigned short Asl[2][512 * 32];
  __shared__ __align__(16) unsigned short Bsl[2][128 * 32];

  const int tid  = threadIdx.x;
  const int lane = tid & 63, wave = tid >> 6;
  const int wm = wave >> 1, wn = wave & 1;       // 4M x 2N
  const int l16 = lane & 15, lk = lane >> 4;
  const int rchunk = ((lk ^ ((l16 ^ (l16 >> 2)) & 3)) & 3) * 8;  // swizzled 16B chunk (ushorts)

  // bijective XCD swizzle (m204): nwg = 1179 = 8*147 + 3
  int orig = blockIdx.x;
  int xcd = orig & 7, local = orig >> 3;
  constexpr int q = NWG / 8, r8 = NWG % 8;
  int wgid = (xcd < r8 ? xcd * (q + 1) : r8 * (q + 1) + (xcd - r8) * q) + local;
  const int tm = (wgid % 3) * 512;   // 3 consecutive wgid share the same B panel
  const int tn = (wgid / 3) * 128;

  f32x4 acc[8][4] = {};

  auto stageA = [&](int t, int s) {
    unsigned short* lb = &Asl[s][0];
    #pragma unroll
    for (int i = 0; i < 4; ++i) {
      int c = i * 512 + tid;                   // 2048 chunks = 32KB
      int rr = c >> 2, qq = c & 3;
      int k8 = qq ^ ((rr ^ (rr >> 2)) & 3);
      gload16(A + (size_t)(tm + rr) * 1024 + t * 32 + k8 * 8, lb + c * 8);
    }
  };
  auto stageB = [&](int t, int s) {
    unsigned short* lb = &Bsl[s][0];
    int c = tid;                               // 512 chunks = 8KB
    int rr = c >> 2, qq = c & 3;
    int k8 = qq ^ ((rr ^ (rr >> 2)) & 3);
    int row = tn + rr; if (row > V - 1) row = V - 1;   // clamp OOB vocab rows
    gload16(E + (size_t)row * 1024 + t * 32 + k8 * 8, lb + c * 8);
  };

  // prologue: step 0 in flight (5 VMEM instrs per wave)
  stageA(0, 0); stageB(0, 0);

  for (int t = 0; t < NT; ++t) {
    int t1 = (t + 1 < NT) ? t + 1 : NT - 1;    // dummy tail keeps vmcnt uniform
    stageA(t1, (t + 1) & 1);                   // slot (t+1)&1 free: prev compute done
    stageB(t1, (t + 1) & 1);
    asm volatile("s_waitcnt vmcnt(5)" ::: "memory");   // step-t loads landed
    __builtin_amdgcn_s_barrier();

    const unsigned short* as = &Asl[t & 1][0];
    const unsigned short* bs = &Bsl[t & 1][0];
    bf16x8 af[8], bg[4];
    #pragma unroll
    for (int mi = 0; mi < 8; ++mi)
      af[mi] = *(const bf16x8*)(as + (wm * 128 + mi * 16 + l16) * 32 + rchunk);
    #pragma unroll
    for (int ni = 0; ni < 4; ++ni)
      bg[ni] = *(const bf16x8*)(bs + (wn * 64 + ni * 16 + l16) * 32 + rchunk);

    __builtin_amdgcn_s_setprio(1);
    #pragma unroll
    for (int mi = 0; mi < 8; ++mi)
      #pragma unroll
      for (int ni = 0; ni < 4; ++ni)
        acc[mi][ni] = __builtin_amdgcn_mfma_f32_16x16x32_bf16(af[mi], bg[ni], acc[mi][ni], 0, 0, 0);
    __builtin_amdgcn_s_setprio(0);
    __builtin_amdgcn_s_barrier();
  }
  asm volatile("s_waitcnt vmcnt(0)" ::: "memory");     // drain dummies before stores/endpgm

  #pragma unroll
  for (int mi = 0; mi < 8; ++mi) {
    #pragma unroll
    for (int rr = 0; rr < 4; ++rr) {
      int row = tm + wm * 128 + mi * 16 + lk * 4 + rr;  // 0..1535 padded
      int kk = row >> 9, bp = row & 511, b = bp >> 8, p = bp & 255;
      if (p >= PLEN) continue;
      size_t obase = ((size_t)((b * PLEN + p) * KD + kk)) * V;
      #pragma unroll
      for (int ni = 0; ni < 4; ++ni) {
        int col = tn + wn * 64 + ni * 16 + l16;
        if (col < V) Out[obase + col] = acc[mi][ni][rr];
      }
    }
  }
}

extern "C" void kernel_launch(void* const* d_in, const int* in_sizes, int n_in,
                              void* d_out, int out_size, void* d_ws, size_t ws_size,
                              hipStream_t stream)
{
  (void)in_sizes; (void)n_in; (void)out_size; (void)ws_size;
  const float* x      = (const float*)d_in[0];
  const float* embedw = (const float*)d_in[1];
  const float* rmsw   = (const float*)d_in[2];
  const float* projw  = (const float*)d_in[3];
  const float* projb  = (const float*)d_in[4];
  const float* ainw   = (const float*)d_in[5];
  const float* ainb   = (const float*)d_in[6];
  const float* aoutw  = (const float*)d_in[7];
  const float* aoutb  = (const float*)d_in[8];
  const float* ff1w   = (const float*)d_in[9];
  const float* ff1b   = (const float*)d_in[10];
  const float* ff2w   = (const float*)d_in[11];
  const float* ff2b   = (const float*)d_in[12];
  const float* ln1w   = (const float*)d_in[13];
  const float* ln1b   = (const float*)d_in[14];
  const float* ln2w   = (const float*)d_in[15];
  const float* ln2b   = (const float*)d_in[16];
  float* out = (float*)d_out;

  char* ws = (char*)d_ws;
  size_t off = 0;
  auto alloc = [&](size_t bytes) -> void* {
    void* ptr = ws + off;
    off = (off + bytes + 255) & ~(size_t)255;
    return ptr;
  };
  unsigned short* embed_b = (unsigned short*)alloc((size_t)V * D * 2);
  unsigned short* projw_b = (unsigned short*)alloc((size_t)KD * D * 2 * D * 2);
  unsigned short* ainw_b  = (unsigned short*)alloc((size_t)KD * D * D * 2);   // V-slice only
  unsigned short* aoutw_b = (unsigned short*)alloc((size_t)KD * D * D * 2);
  unsigned short* ff1w_b  = (unsigned short*)alloc((size_t)KD * DFF * D * 2);
  unsigned short* ff2w_b  = (unsigned short*)alloc((size_t)KD * D * DFF * 2);
  float*          h_f     = (float*)alloc((size_t)MR * D * 4);
  unsigned short* h_all   = (unsigned short*)alloc((size_t)KD * MR * D * 2);
  unsigned short* merged  = (unsigned short*)alloc((size_t)MR * 2 * D * 2);
  float*          p_f     = (float*)alloc((size_t)MR * D * 4);
  unsigned short* p_b     = (unsigned short*)alloc((size_t)MR * D * 2);
  unsigned short* v_b     = (unsigned short*)alloc((size_t)MR * D * 2);
  float*          sa_f    = (float*)alloc((size_t)MR * D * 4);
  float*          s1_f    = (float*)alloc((size_t)MR * D * 4);
  unsigned short* s1_b    = (unsigned short*)alloc((size_t)MR * D * 2);
  unsigned short* ff_b    = (unsigned short*)alloc((size_t)MR * DFF * 2);
  float*          ff2_f   = (float*)alloc((size_t)MR * D * 4);

  auto cvt = [&](const float* s, unsigned short* dgt, long n) {
    long n4 = n / 4;
    int blocks = (int)((n4 + 255) / 256);
    if (blocks > 4096) blocks = 4096;
    cvt_bf16<<<dim3(blocks), dim3(256), 0, stream>>>(s, dgt, (int)n);
  };
  cvt(embedw, embed_b, (long)V * D);
  cvt(projw,  projw_b, (long)KD * D * 2 * D);
  for (int k = 0; k < KD; ++k)   // only the V-slice attn_in_w[k][2D:] is used
    cvt(ainw + (size_t)k * 3 * D * D + (size_t)2 * D * D, ainw_b + (size_t)k * D * D, (long)D * D);
  cvt(aoutw,  aoutw_b, (long)KD * D * D);
  cvt(ff1w,   ff1w_b,  (long)KD * DFF * D);
  cvt(ff2w,   ff2w_b,  (long)KD * D * DFF);

  init_h<<<dim3(MR), dim3(256), 0, stream>>>(x, h_f);

  for (int k = 0; k < KD; ++k) {
    rms_merge<<<dim3(MR), dim3(256), 0, stream>>>(h_f, x, rmsw, merged, k);
    // p = merged @ proj_w[k]^T + proj_b[k]   (M=512, N=1024, K=2048)
    gemm2<true,false,true,true><<<dim3(D/64, MR/64), dim3(256), 0, stream>>>(
        merged, projw_b + (size_t)k * D * 2 * D, projb + (size_t)k * D, p_f, p_b, D, 2 * D);
    // v = p @ wv^T + bv  (wv = attn_in_w[k][2D:], 1024x1024)
    gemm2<true,false,false,true><<<dim3(D/64, MR/64), dim3(256), 0, stream>>>(
        p_b, ainw_b + (size_t)k * D * D, ainb + (size_t)k * 3 * D + 2 * D,
        (float*)nullptr, v_b, D, D);
    // sa = v @ attn_out_w[k]^T + b
    gemm2<true,false,true,false><<<dim3(D/64, MR/64), dim3(256), 0, stream>>>(
        v_b, aoutw_b + (size_t)k * D * D, aoutb + (size_t)k * D, sa_f, (unsigned short*)nullptr, D, D);
    // s1 = LN(p + sa)
    add_ln<<<dim3(MR), dim3(256), 0, stream>>>(p_f, sa_f, ln1w + (size_t)k * D, ln1b + (size_t)k * D, s1_f, s1_b);
    // ff = relu(s1 @ ff1_w[k]^T + b)   (N=2048)
    gemm2<true,true,false,true><<<dim3(DFF/64, MR/64), dim3(256), 0, stream>>>(
        s1_b, ff1w_b + (size_t)k * DFF * D, ff1b + (size_t)k * DFF, (float*)nullptr, ff_b, DFF, D);
    // ff2 = ff @ ff2_w[k]^T + b        (K=2048)
    gemm2<true,false,true,false><<<dim3(D/64, MR/64), dim3(256), 0, stream>>>(
        ff_b, ff2w_b + (size_t)k * D * DFF, ff2b + (size_t)k * D, ff2_f, (unsigned short*)nullptr, D, 2 * D);
    // h = LN(s1 + ff2) -> h_f (f32, next iter) + h_all[k] (bf16, logits)
    add_ln<<<dim3(MR), dim3(256), 0, stream>>>(s1_f, ff2_f, ln2w + (size_t)k * D, ln2b + (size_t)k * D,
                                               h_f, h_all + (size_t)k * MR * D);
  }

  // logits for all 3 depths: (1536 x 1024) @ (50257 x 1024)^T, BM=512, 2 blocks/CU
  gemm_logits5<<<dim3(3 * 393), dim3(512), 0, stream>>>(h_all, embed_b, out);
}